// Round 2
// baseline (220.943 us; speedup 1.0000x reference)
//
#include <hip/hip_runtime.h>
#include <hip/hip_cooperative_groups.h>
#include <math.h>

namespace cg = cooperative_groups;

#define NB 4
#define NT 1024
#define NPIX 1296
#define NBINS 512
#define LOOKUP 101
#define PADW 50
#define ODIM 128
#define MT 16                 // t-rows per sims tile
#define WPAD 104              // win_s row stride (floats)
#define NBLK 256              // one block per sims tile; 16 frames hist each
#define NTHR 512

typedef _Float16 v8h __attribute__((ext_vector_type(8)));
typedef float v4f __attribute__((ext_vector_type(4)));

// Fused single-dispatch kernel, grid-wide sync via cooperative groups.
// Block bid owns tile = xcd-swizzled(bid): phase 1 computes that tile's 16
// normalized histograms (X rows), phase 2 computes its banded sims + FC.
// Producer rows stay in the producing XCD's L2 across the sync.
__global__ __launch_bounds__(NTHR) void fused_kernel(const int* __restrict__ frames,
                                                     unsigned short* __restrict__ X,
                                                     const float* __restrict__ w,
                                                     const float* __restrict__ bias,
                                                     float* __restrict__ out) {
    const int tid = threadIdx.x;
    const int wv = tid >> 6;          // wave 0..7
    const int lane = tid & 63;
    const int bid = blockIdx.x;
    // XCD swizzle: 32 consecutive tiles (512 t's) per XCD; bijective (256 % 8 == 0)
    const int tile = ((bid & 7) << 5) | (bid >> 3);    // 0..255
    const int b = tile >> 6;                            // 64 tiles per batch
    const int t0 = (tile & 63) * MT;

    __shared__ unsigned int hist[8][NBINS];   // 16 KB, wave-private rows
    __shared__ float win_s[MT][WPAD];         // 6.5 KB

    // ---------------- Phase 1: 16 histograms (wave -> 2 frames, sequential) ----
    unsigned int* h = hist[wv];
#pragma unroll
    for (int rep = 0; rep < 2; ++rep) {
        const int frame = 16 * tile + 2 * wv + rep;

#pragma unroll
        for (int k = 0; k < NBINS / 64; ++k) h[lane + 64 * k] = 0u;

        const int4* f4 = (const int4*)(frames + (size_t)frame * NPIX * 3);
#pragma unroll
        for (int it = 0; it < 5; ++it) {       // uniform iters: int4-groups 0..319
            const int g = lane + 64 * it;
            int4 a = f4[g * 3 + 0];
            int4 bb = f4[g * 3 + 1];
            int4 c = f4[g * 3 + 2];
            int v[12] = {a.x, a.y, a.z, a.w, bb.x, bb.y, bb.z, bb.w, c.x, c.y, c.z, c.w};
#pragma unroll
            for (int p = 0; p < 4; ++p) {
                int bin = ((v[3 * p] >> 5) << 6) | ((v[3 * p + 1] >> 5) << 3) | (v[3 * p + 2] >> 5);
                atomicAdd(&h[bin], 1u);
            }
        }
        if (lane < 4) {                         // tail: groups 320..323
            const int g = 320 + lane;
            int4 a = f4[g * 3 + 0];
            int4 bb = f4[g * 3 + 1];
            int4 c = f4[g * 3 + 2];
            int v[12] = {a.x, a.y, a.z, a.w, bb.x, bb.y, bb.z, bb.w, c.x, c.y, c.z, c.w};
#pragma unroll
            for (int p = 0; p < 4; ++p) {
                int bin = ((v[3 * p] >> 5) << 6) | ((v[3 * p + 1] >> 5) << 3) | (v[3 * p + 2] >> 5);
                atomicAdd(&h[bin], 1u);
            }
        }

        float cnt[8];
        float local = 0.f;
#pragma unroll
        for (int k = 0; k < 8; ++k) {
            cnt[k] = (float)h[lane + 64 * k];
            local += cnt[k] * cnt[k];
        }
        for (int off = 32; off >= 1; off >>= 1) local += __shfl_xor(local, off, 64);
        const float inv = 1.0f / fmaxf(sqrtf(local), 1e-12f);

        unsigned short* xr = X + (size_t)frame * NBINS;
#pragma unroll
        for (int k = 0; k < 8; ++k) {
            union { _Float16 h16; unsigned short u; } cv;
            cv.h16 = (_Float16)(cnt[k] * inv);
            xr[lane + 64 * k] = cv.u;
        }
    }

    // ---------------- grid-wide barrier: all X rows visible device-wide --------
    __threadfence();
    cg::this_grid().sync();

    // ---------------- Phase 2: banded sims via MFMA + FC + ReLU ----------------
    // wave w owns n-tile w (cols 16w..16w+15); C[16x128] = A[16x512]*B[512x128]
    const _Float16* Xh = (const _Float16*)X + (size_t)b * NT * NBINS;
    const int L = tid & 63;
    const int ntile = tid >> 6;        // 0..7

    const _Float16* Ap = Xh + (size_t)(t0 + (L & 15)) * NBINS + 8 * (L >> 4);
    const int n = ntile * 16 + (L & 15);
    const int jl = t0 - PADW + n;
    const int jc = min(max(jl, 0), NT - 1);
    const _Float16* Bp = Xh + (size_t)jc * NBINS + 8 * (L >> 4);

    v4f acc = {0.f, 0.f, 0.f, 0.f};
#pragma unroll
    for (int s = 0; s < 16; ++s) {
        v8h a = *(const v8h*)(Ap + 32 * s);
        v8h bb = *(const v8h*)(Bp + 32 * s);
        acc = __builtin_amdgcn_mfma_f32_16x16x32_f16(a, bb, acc, 0, 0, 0);
    }

    // scatter into win_s (one writer per (m,l): n = m + l unique)
    const bool jvalid = (jl >= 0) && (jl < NT);
#pragma unroll
    for (int r = 0; r < 4; ++r) {
        const int m = 4 * (L >> 4) + r;
        const int l = n - m;
        if ((unsigned)l <= 100u) win_s[m][l] = jvalid ? acc[r] : 0.f;
    }
    __syncthreads();

    // FC + ReLU: thread -> (m = tid>>5, 4 channels); w rows L2-resident
    const int m = tid >> 5;
    const int ch = (tid & 31) * 4;
    v4f a4 = *(const v4f*)(bias + ch);
#pragma unroll 4
    for (int l = 0; l < LOOKUP; ++l) {
        float wl = win_s[m][l];
        v4f wv4 = *(const v4f*)(w + l * ODIM + ch);
        a4.x = fmaf(wl, wv4.x, a4.x);
        a4.y = fmaf(wl, wv4.y, a4.y);
        a4.z = fmaf(wl, wv4.z, a4.z);
        a4.w = fmaf(wl, wv4.w, a4.w);
    }
    a4.x = fmaxf(a4.x, 0.f); a4.y = fmaxf(a4.y, 0.f);
    a4.z = fmaxf(a4.z, 0.f); a4.w = fmaxf(a4.w, 0.f);
    *(v4f*)(out + (size_t)(b * NT + t0 + m) * ODIM + ch) = a4;
}

extern "C" void kernel_launch(void* const* d_in, const int* in_sizes, int n_in,
                              void* d_out, int out_size, void* d_ws, size_t ws_size,
                              hipStream_t stream) {
    const int*   frames = (const int*)d_in[0];
    const float* fc_w   = (const float*)d_in[1];
    const float* fc_b   = (const float*)d_in[2];
    float* out = (float*)d_out;

    unsigned short* X = (unsigned short*)d_ws;   // 4096*512 f16 = 4 MB of workspace

    void* args[] = {(void*)&frames, (void*)&X, (void*)&fc_w, (void*)&fc_b, (void*)&out};
    hipLaunchCooperativeKernel((void*)fused_kernel, dim3(NBLK), dim3(NTHR),
                               args, 0, stream);
}

// Round 3
// 113.187 us; speedup vs baseline: 1.9520x; 1.9520x over previous
//
#include <hip/hip_runtime.h>
#include <math.h>

#define NB 4
#define NT 1024
#define NPIX 1296
#define NBINS 512
#define LOOKUP 101
#define PADW 50
#define ODIM 128
#define MT 16                 // t-rows per sims block (MFMA M-tile)
#define WPAD 104              // win_s row stride (floats)

typedef _Float16 v8h __attribute__((ext_vector_type(8)));
typedef float v4f __attribute__((ext_vector_type(4)));

// ---------------- Kernel A: wave-private histograms, zero block barriers.
// (3 structural variants benched equal -> HBM/limiter floor. Pixel loop is
// 5 compile-time iters + 4-lane tail for static addressing / load hoisting.)
__global__ __launch_bounds__(256) void hist_kernel(const int* __restrict__ frames,
                                                   unsigned short* __restrict__ X) {
    const int wv = threadIdx.x >> 6;
    const int lane = threadIdx.x & 63;
    const int frame = blockIdx.x * 4 + wv;

    __shared__ unsigned int hist[4][NBINS];
    unsigned int* h = hist[wv];

#pragma unroll
    for (int k = 0; k < NBINS / 64; ++k) h[lane + 64 * k] = 0u;

    const int4* f4 = (const int4*)(frames + (size_t)frame * NPIX * 3);
#pragma unroll
    for (int it = 0; it < 5; ++it) {            // uniform iters: int4-groups 0..319
        const int g = lane + 64 * it;
        int4 a = f4[g * 3 + 0];
        int4 b = f4[g * 3 + 1];
        int4 c = f4[g * 3 + 2];
        int v[12] = {a.x, a.y, a.z, a.w, b.x, b.y, b.z, b.w, c.x, c.y, c.z, c.w};
#pragma unroll
        for (int p = 0; p < 4; ++p) {
            int bin = ((v[3 * p] >> 5) << 6) | ((v[3 * p + 1] >> 5) << 3) | (v[3 * p + 2] >> 5);
            atomicAdd(&h[bin], 1u);
        }
    }
    if (lane < 4) {                              // tail: groups 320..323
        const int g = 320 + lane;
        int4 a = f4[g * 3 + 0];
        int4 b = f4[g * 3 + 1];
        int4 c = f4[g * 3 + 2];
        int v[12] = {a.x, a.y, a.z, a.w, b.x, b.y, b.z, b.w, c.x, c.y, c.z, c.w};
#pragma unroll
        for (int p = 0; p < 4; ++p) {
            int bin = ((v[3 * p] >> 5) << 6) | ((v[3 * p + 1] >> 5) << 3) | (v[3 * p + 2] >> 5);
            atomicAdd(&h[bin], 1u);
        }
    }

    float cnt[8];
    float local = 0.f;
#pragma unroll
    for (int k = 0; k < 8; ++k) {
        cnt[k] = (float)h[lane + 64 * k];
        local += cnt[k] * cnt[k];
    }
    for (int off = 32; off >= 1; off >>= 1) local += __shfl_xor(local, off, 64);
    float inv = 1.0f / fmaxf(sqrtf(local), 1e-12f);

    unsigned short* xr = X + (size_t)frame * NBINS;
#pragma unroll
    for (int k = 0; k < 8; ++k) {
        union { _Float16 h16; unsigned short u; } cv;
        cv.h16 = (_Float16)(cnt[k] * inv);
        xr[lane + 64 * k] = cv.u;
    }
}

// ---------------- Kernel B: MFMA banded sims + VALU FC + ReLU.
// Block = 16 t-rows, 512 threads = 8 waves; wave w owns n-tile w (cols 16w..16w+15).
// C[16x128] = A[16x512] * B[512x128], K-steps of 32 via mfma_f32_16x16x32_f16.
// Epilogue: C elem (reg r, lane L) is sims for m=4*(L>>4)+r, n=ntile*16+(L&15);
// win l = n - m, j = t0 - 50 + n.
__global__ __launch_bounds__(512) void simsfc_kernel(const unsigned short* __restrict__ Xu,
                                                     const float* __restrict__ w,
                                                     const float* __restrict__ bias,
                                                     float* __restrict__ out) {
    const int bid = blockIdx.x;
    // XCD swizzle: 32 consecutive tiles (512 t's) per XCD -> B-window slice L2-resident
    const int tile = ((bid & 7) << 5) | (bid >> 3);    // 0..255
    const int b = tile >> 6;                            // 64 tiles per batch
    const int t0 = (tile & 63) * MT;
    const int tid = threadIdx.x;
    const int L = tid & 63;
    const int ntile = tid >> 6;        // 0..7

    const _Float16* Xh = (const _Float16*)Xu + (size_t)b * NT * NBINS;

    __shared__ float win_s[MT][WPAD];

    // fragment base pointers (immediate-offset friendly: +64B per k-step)
    const _Float16* Ap = Xh + (size_t)(t0 + (L & 15)) * NBINS + 8 * (L >> 4);
    const int n = ntile * 16 + (L & 15);
    const int jl = t0 - PADW + n;
    const int jc = min(max(jl, 0), NT - 1);
    const _Float16* Bp = Xh + (size_t)jc * NBINS + 8 * (L >> 4);

    v4f acc = {0.f, 0.f, 0.f, 0.f};
#pragma unroll
    for (int s = 0; s < 16; ++s) {
        v8h a = *(const v8h*)(Ap + 32 * s);
        v8h bb = *(const v8h*)(Bp + 32 * s);
        acc = __builtin_amdgcn_mfma_f32_16x16x32_f16(a, bb, acc, 0, 0, 0);
    }

    // epilogue: scatter into win_s (one writer per (m,l) cell; n = m + l unique)
    const bool jvalid = (jl >= 0) && (jl < NT);
#pragma unroll
    for (int r = 0; r < 4; ++r) {
        const int m = 4 * (L >> 4) + r;
        const int l = n - m;
        if ((unsigned)l <= 100u) win_s[m][l] = jvalid ? acc[r] : 0.f;
    }
    __syncthreads();

    // FC + ReLU: thread -> (m = tid>>5, 4 channels). w rows L2-resident.
    const int m = tid >> 5;
    const int ch = (tid & 31) * 4;
    v4f a4 = *(const v4f*)(bias + ch);
#pragma unroll 4
    for (int l = 0; l < LOOKUP; ++l) {
        float wl = win_s[m][l];
        v4f wv = *(const v4f*)(w + l * ODIM + ch);
        a4.x = fmaf(wl, wv.x, a4.x);
        a4.y = fmaf(wl, wv.y, a4.y);
        a4.z = fmaf(wl, wv.z, a4.z);
        a4.w = fmaf(wl, wv.w, a4.w);
    }
    a4.x = fmaxf(a4.x, 0.f); a4.y = fmaxf(a4.y, 0.f);
    a4.z = fmaxf(a4.z, 0.f); a4.w = fmaxf(a4.w, 0.f);
    *(v4f*)(out + (size_t)(b * NT + t0 + m) * ODIM + ch) = a4;
}

extern "C" void kernel_launch(void* const* d_in, const int* in_sizes, int n_in,
                              void* d_out, int out_size, void* d_ws, size_t ws_size,
                              hipStream_t stream) {
    const int*   frames = (const int*)d_in[0];
    const float* fc_w   = (const float*)d_in[1];
    const float* fc_b   = (const float*)d_in[2];
    float* out = (float*)d_out;

    unsigned short* X = (unsigned short*)d_ws;   // 4096*512 f16 = 4 MB of workspace

    hist_kernel  <<<NB * NT / 4, 256, 0, stream>>>(frames, X);
    simsfc_kernel<<<NB * NT / MT, 512, 0, stream>>>(X, fc_w, fc_b, out);
}